// Round 3
// baseline (432.164 us; speedup 1.0000x reference)
//
#include <hip/hip_runtime.h>
#include <math.h>

#define VOCAB 30000
#define EMB   100
#define HID   128
#define BATCH 1024
#define SEQ   512

typedef float f32x4 __attribute__((ext_vector_type(4)));

// Kernel A: EWx[v][j] = sum_e E[v][e]*Wx[e][j] + b[j]   (folds bias in)
__global__ __launch_bounds__(256) void ewx_kernel(
    const float* __restrict__ E, const float* __restrict__ Wx,
    const float* __restrict__ bias, float* __restrict__ EWx)
{
    __shared__ float Es[64][EMB];     // 25.6 KB
    __shared__ float Wxs[EMB][HID];   // 51.2 KB
    const int tid = threadIdx.x;
    const int v0 = blockIdx.x * 64;
    const int nv = min(64, VOCAB - v0);

    {
        const float4* s4 = (const float4*)Wx;
        float4* d4 = (float4*)(&Wxs[0][0]);
        for (int i = tid; i < (EMB * HID) / 4; i += 256) d4[i] = s4[i];
    }
    {
        const float* src = E + (size_t)v0 * EMB;
        float* dst = &Es[0][0];
        const int n  = nv * EMB;
        const int n4 = n >> 2;
        const float4* s4 = (const float4*)src;
        float4* d4 = (float4*)dst;
        for (int i = tid; i < n4; i += 256) d4[i] = s4[i];
        for (int i = (n4 << 2) + tid; i < n; i += 256) dst[i] = src[i];
    }
    __syncthreads();

    const int j  = tid & 127;
    const int vh = tid >> 7;
    float acc[32];
#pragma unroll
    for (int m = 0; m < 32; ++m) acc[m] = 0.f;

    for (int k4 = 0; k4 < EMB; k4 += 4) {
        const float w0 = Wxs[k4 + 0][j];
        const float w1 = Wxs[k4 + 1][j];
        const float w2 = Wxs[k4 + 2][j];
        const float w3 = Wxs[k4 + 3][j];
#pragma unroll
        for (int m = 0; m < 32; ++m) {
            const float4 e = *(const float4*)&Es[vh + 2 * m][k4];
            acc[m] = fmaf(e.x, w0, acc[m]);
            acc[m] = fmaf(e.y, w1, acc[m]);
            acc[m] = fmaf(e.z, w2, acc[m]);
            acc[m] = fmaf(e.w, w3, acc[m]);
        }
    }
    const float bj = bias[j];
#pragma unroll
    for (int m = 0; m < 32; ++m) {
        const int v = vh + 2 * m;
        if (v < nv)
            EWx[(size_t)(v0 + v) * HID + j] = acc[m] + bj;
    }
}

// Kernel B: sequential recurrence.
// Block = 256 threads, 2 batch rows. Thread: rr = tid>>7 (batch row),
// jg = (tid&127)>>2 (column quad), kq = tid&3 (k-quarter).
// Thread FMA-owns columns 4jg..4jg+3 over k in [kq*32, kq*32+32):
//   Wh slice = 32 x float4 = 128 VGPRs, PINNED via asm (round-2 showed the
//   compiler remats global loads into the loop otherwise: VGPR_Count was 84).
// Per step: 8x ds_read_b128 of h (broadcast) -> 128 FMAs -> 2-round
// __shfl_xor reduce over the lane quad -> each lane finalizes col 4jg+kq
// (tanh) -> write h_new. ONE barrier per step (double-buffered h).
__global__ __launch_bounds__(256, 2) void rnn_kernel(
    const int* __restrict__ X, const float* __restrict__ EWx,
    const float* __restrict__ Wh, const float* __restrict__ Wd,
    const float* __restrict__ bd, float* __restrict__ out)
{
    __shared__ __align__(16) float hbuf[2][2][HID]; // 2 KB, double-buffered
    __shared__ int idx[2][SEQ];                     // 4 KB token indices

    const int tid = threadIdx.x;
    const int rr  = tid >> 7;          // batch row within block (0/1)
    const int l   = tid & 127;
    const int jg  = l >> 2;            // column quad (0..31)
    const int kq  = l & 3;             // k-quarter (0..3)
    const int b0  = blockIdx.x * 2;

    for (int i = tid; i < 2 * SEQ; i += 256) {
        const int bb = i >> 9;
        const int tt = i & (SEQ - 1);
        idx[bb][tt] = X[(size_t)(b0 + bb) * SEQ + tt];
    }

    // Wh[kq*32+kk][4jg .. 4jg+3] -> 32 float4 (coalesced dwordx4 over jg)
    f32x4 wh[32];
#pragma unroll
    for (int kk = 0; kk < 32; ++kk)
        wh[kk] = *reinterpret_cast<const f32x4*>(
            &Wh[(size_t)(kq * 32 + kk) * HID + 4 * jg]);
    // Pin: opaque redefinition prevents rematerialization of the loads.
#pragma unroll
    for (int kk = 0; kk < 32; ++kk)
        asm volatile("" : "+v"(wh[kk]));

    (&hbuf[0][0][0])[tid] = 0.f;       // h0 = 0 (256 floats)
    __syncthreads();

    const float* hb_base = &hbuf[0][rr][kq * 32];   // k-slice read base
    float*       hw_base = &hbuf[0][rr][4 * jg + kq]; // final-col write base
    const int    jf      = 4 * jg + kq;

    int cur = 0;
    for (int t = 0; t < SEQ; ++t) {
        // prefetch xp (L2/L3 hit) — consumed after the FMA loop
        const int   tok = idx[rr][t];
        const float xp  = EWx[(size_t)tok * HID + jf];

        const f32x4* h4 = reinterpret_cast<const f32x4*>(hb_base + cur * 256);
        float a0 = 0.f, a1 = 0.f, a2 = 0.f, a3 = 0.f; // 4 owned columns
#pragma unroll
        for (int q = 0; q < 8; ++q) {
            const f32x4 u = h4[q];     // broadcast ds_read_b128
#define RNN_STEP(m) { const f32x4 w = wh[4 * q + m]; const float hv = u[m]; \
            a0 = fmaf(hv, w.x, a0); a1 = fmaf(hv, w.y, a1);                 \
            a2 = fmaf(hv, w.z, a2); a3 = fmaf(hv, w.w, a3); }
            RNN_STEP(0) RNN_STEP(1) RNN_STEP(2) RNN_STEP(3)
#undef RNN_STEP
        }
        // reduce over k-quarters: lanes in a quad differ only in kq
        a0 += __shfl_xor(a0, 1); a1 += __shfl_xor(a1, 1);
        a2 += __shfl_xor(a2, 1); a3 += __shfl_xor(a3, 1);
        a0 += __shfl_xor(a0, 2); a1 += __shfl_xor(a1, 2);
        a2 += __shfl_xor(a2, 2); a3 += __shfl_xor(a3, 2);

        const float v = (kq == 0) ? a0 : (kq == 1) ? a1 : (kq == 2) ? a2 : a3;
        const float s  = v + xp;
        const float x  = fminf(fmaxf(s, -9.f), 9.f);  // tanh saturates past 9
        const float e2 = __expf(2.f * x);
        hw_base[(cur ^ 1) * 256] = __fdividef(e2 - 1.f, e2 + 1.f);
        __syncthreads();
        cur ^= 1;
    }

    // head: out[b] = sigmoid(h . Wd + bd)
    if (tid < 128) {
        const int bb   = tid >> 6;
        const int lane = tid & 63;
        const float* hb = hbuf[cur][bb];
        float v = hb[lane] * Wd[lane] + hb[lane + 64] * Wd[lane + 64];
#pragma unroll
        for (int off = 32; off > 0; off >>= 1)
            v += __shfl_down(v, off, 64);
        if (lane == 0)
            out[b0 + bb] = 1.0f / (1.0f + expf(-(v + bd[0])));
    }
}

extern "C" void kernel_launch(void* const* d_in, const int* in_sizes, int n_in,
                              void* d_out, int out_size, void* d_ws, size_t ws_size,
                              hipStream_t stream)
{
    const int*   X  = (const int*)d_in[0];
    const float* E  = (const float*)d_in[1];
    const float* Wx = (const float*)d_in[2];
    const float* Wh = (const float*)d_in[3];
    const float* b  = (const float*)d_in[4];
    const float* Wd = (const float*)d_in[5];
    const float* bd = (const float*)d_in[6];
    float* out = (float*)d_out;
    float* EWx = (float*)d_ws;   // 30000*128*4 = 15.36 MB scratch

    ewx_kernel<<<dim3((VOCAB + 63) / 64), dim3(256), 0, stream>>>(E, Wx, b, EWx);
    rnn_kernel<<<dim3(BATCH / 2), dim3(256), 0, stream>>>(X, EWx, Wh, Wd, bd, out);
}

// Round 4
// 358.570 us; speedup vs baseline: 1.2052x; 1.2052x over previous
//
#include <hip/hip_runtime.h>
#include <math.h>

#define VOCAB 30000
#define EMB   100
#define HID   128
#define BATCH 1024
#define SEQ   512

typedef float f32x4 __attribute__((ext_vector_type(4)));

// Kernel A: EWx[v][j] = sum_e E[v][e]*Wx[e][j] + b[j]   (folds bias in)
__global__ __launch_bounds__(256) void ewx_kernel(
    const float* __restrict__ E, const float* __restrict__ Wx,
    const float* __restrict__ bias, float* __restrict__ EWx)
{
    __shared__ float Es[64][EMB];     // 25.6 KB
    __shared__ float Wxs[EMB][HID];   // 51.2 KB
    const int tid = threadIdx.x;
    const int v0 = blockIdx.x * 64;
    const int nv = min(64, VOCAB - v0);

    {
        const float4* s4 = (const float4*)Wx;
        float4* d4 = (float4*)(&Wxs[0][0]);
        for (int i = tid; i < (EMB * HID) / 4; i += 256) d4[i] = s4[i];
    }
    {
        const float* src = E + (size_t)v0 * EMB;
        float* dst = &Es[0][0];
        const int n  = nv * EMB;
        const int n4 = n >> 2;
        const float4* s4 = (const float4*)src;
        float4* d4 = (float4*)dst;
        for (int i = tid; i < n4; i += 256) d4[i] = s4[i];
        for (int i = (n4 << 2) + tid; i < n; i += 256) dst[i] = src[i];
    }
    __syncthreads();

    const int j  = tid & 127;
    const int vh = tid >> 7;
    float acc[32];
#pragma unroll
    for (int m = 0; m < 32; ++m) acc[m] = 0.f;

    for (int k4 = 0; k4 < EMB; k4 += 4) {
        const float w0 = Wxs[k4 + 0][j];
        const float w1 = Wxs[k4 + 1][j];
        const float w2 = Wxs[k4 + 2][j];
        const float w3 = Wxs[k4 + 3][j];
#pragma unroll
        for (int m = 0; m < 32; ++m) {
            const float4 e = *(const float4*)&Es[vh + 2 * m][k4];
            acc[m] = fmaf(e.x, w0, acc[m]);
            acc[m] = fmaf(e.y, w1, acc[m]);
            acc[m] = fmaf(e.z, w2, acc[m]);
            acc[m] = fmaf(e.w, w3, acc[m]);
        }
    }
    const float bj = bias[j];
#pragma unroll
    for (int m = 0; m < 32; ++m) {
        const int v = vh + 2 * m;
        if (v < nv)
            EWx[(size_t)(v0 + v) * HID + j] = acc[m] + bj;
    }
}

// Kernel B: sequential recurrence.
// Block = 256 threads, 2 batch rows. Thread = (kq = tid>>5 in 0..7,
// jc = tid&31): owns Wh[kq*16 .. +15][4jc .. 4jc+3] = 64 floats in VGPRs
// (HALVED vs round 3's 128 — the allocator spilled 128 asm-pinned weights
// to scratch, VGPR_Count=80). Each thread computes partials for BOTH batch
// rows from the same weights (128 FMA/step as before).
// h-reads: per wave only 2 distinct addresses (kq in {2w,2w+1}) at 64B
// stride -> different banks, conflict-free (round 3's kq=tid&3 layout was
// a 4-way conflict: 3.36e7 conflict cycles).
// 8-way k-reduce through part[2][8][HID] (b128 writes contiguous, b32
// reads stride-1, both conflict-free), then tanh, h_new write, 2 barriers.
__global__ __launch_bounds__(256, 2) void rnn_kernel(
    const int* __restrict__ X, const float* __restrict__ EWx,
    const float* __restrict__ Wh, const float* __restrict__ Wd,
    const float* __restrict__ bd, float* __restrict__ out)
{
    __shared__ __align__(16) float hbuf[2][2][HID];  // 2 KB, double-buffered
    __shared__ __align__(16) float part[2][8][HID];  // 8 KB partials
    __shared__ int idx[2][SEQ];                      // 4 KB token indices

    const int tid = threadIdx.x;
    const int kq  = tid >> 5;          // k-slice [kq*16, kq*16+16)
    const int jc  = tid & 31;          // column quad: cols 4jc..4jc+3
    const int b0  = blockIdx.x * 2;

    for (int i = tid; i < 2 * SEQ; i += 256) {
        idx[i >> 9][i & 511] = X[(size_t)(b0 + (i >> 9)) * SEQ + (i & 511)];
    }

    // Wh[kq*16+kk][4jc..4jc+3] -> 64 scalar VGPRs (loaded as coalesced x4)
    float wh[64];
#pragma unroll
    for (int kk = 0; kk < 16; ++kk) {
        const f32x4 w = *reinterpret_cast<const f32x4*>(
            &Wh[(size_t)(kq * 16 + kk) * HID + 4 * jc]);
        wh[kk * 4 + 0] = w.x; wh[kk * 4 + 1] = w.y;
        wh[kk * 4 + 2] = w.z; wh[kk * 4 + 3] = w.w;
    }
    // Pin as individual floats (no tuple-alignment pressure on the allocator)
#pragma unroll
    for (int i = 0; i < 64; ++i) asm volatile("" : "+v"(wh[i]));

    (&hbuf[0][0][0])[tid] = 0.f;       // h0 = 0 (256 floats)
    __syncthreads();

    const int rf = tid >> 7;           // row this thread finalizes
    const int cf = tid & 127;          // column this thread finalizes

    int cur = 0;
    for (int t = 0; t < SEQ; ++t) {
        // issue xp gather early; consumed at finalize (hidden under FMAs)
        const int   tok = idx[rf][t];
        const float xp  = EWx[(size_t)tok * HID + cf];

        const f32x4* h0 = (const f32x4*)&hbuf[cur][0][kq * 16];
        const f32x4* h1 = (const f32x4*)&hbuf[cur][1][kq * 16];
        float a00 = 0.f, a01 = 0.f, a02 = 0.f, a03 = 0.f;  // row 0, 4 cols
        float a10 = 0.f, a11 = 0.f, a12 = 0.f, a13 = 0.f;  // row 1, 4 cols
#pragma unroll
        for (int q = 0; q < 4; ++q) {
            const f32x4 u0 = h0[q];    // broadcast ds_read_b128 (2 addrs/wave)
            const f32x4 u1 = h1[q];
#pragma unroll
            for (int m = 0; m < 4; ++m) {
                const float hv0 = u0[m], hv1 = u1[m];
                const int kk = 4 * q + m;
                const float w0 = wh[kk*4+0], w1 = wh[kk*4+1];
                const float w2 = wh[kk*4+2], w3 = wh[kk*4+3];
                a00 = fmaf(hv0, w0, a00); a01 = fmaf(hv0, w1, a01);
                a02 = fmaf(hv0, w2, a02); a03 = fmaf(hv0, w3, a03);
                a10 = fmaf(hv1, w0, a10); a11 = fmaf(hv1, w1, a11);
                a12 = fmaf(hv1, w2, a12); a13 = fmaf(hv1, w3, a13);
            }
        }
        // contiguous b128 partial writes (conflict-free)
        { f32x4 p0; p0.x = a00; p0.y = a01; p0.z = a02; p0.w = a03;
          *reinterpret_cast<f32x4*>(&part[0][kq][4 * jc]) = p0; }
        { f32x4 p1; p1.x = a10; p1.y = a11; p1.z = a12; p1.w = a13;
          *reinterpret_cast<f32x4*>(&part[1][kq][4 * jc]) = p1; }
        __syncthreads();

        // finalize (rf, cf): 8-way reduce (stride-1 b32 reads) + xp + tanh
        float s = xp;
#pragma unroll
        for (int k = 0; k < 8; ++k) s += part[rf][k][cf];
        const float x  = fminf(fmaxf(s, -9.f), 9.f);  // tanh saturates past 9
        const float e2 = __expf(2.f * x);
        hbuf[cur ^ 1][rf][cf] = __fdividef(e2 - 1.f, e2 + 1.f);
        __syncthreads();
        cur ^= 1;
    }

    // head: out[b] = sigmoid(h . Wd + bd)
    if (tid < 128) {
        const int bb   = tid >> 6;
        const int lane = tid & 63;
        const float* hb = hbuf[cur][bb];
        float v = hb[lane] * Wd[lane] + hb[lane + 64] * Wd[lane + 64];
#pragma unroll
        for (int off = 32; off > 0; off >>= 1)
            v += __shfl_down(v, off, 64);
        if (lane == 0)
            out[b0 + bb] = 1.0f / (1.0f + expf(-(v + bd[0])));
    }
}

extern "C" void kernel_launch(void* const* d_in, const int* in_sizes, int n_in,
                              void* d_out, int out_size, void* d_ws, size_t ws_size,
                              hipStream_t stream)
{
    const int*   X  = (const int*)d_in[0];
    const float* E  = (const float*)d_in[1];
    const float* Wx = (const float*)d_in[2];
    const float* Wh = (const float*)d_in[3];
    const float* b  = (const float*)d_in[4];
    const float* Wd = (const float*)d_in[5];
    const float* bd = (const float*)d_in[6];
    float* out = (float*)d_out;
    float* EWx = (float*)d_ws;   // 30000*128*4 = 15.36 MB scratch

    ewx_kernel<<<dim3((VOCAB + 63) / 64), dim3(256), 0, stream>>>(E, Wx, b, EWx);
    rnn_kernel<<<dim3(BATCH / 2), dim3(256), 0, stream>>>(X, EWx, Wh, Wd, bd, out);
}

// Round 5
// 358.472 us; speedup vs baseline: 1.2056x; 1.0003x over previous
//
#include <hip/hip_runtime.h>
#include <math.h>

#define VOCAB 30000
#define EMB   100
#define HID   128
#define BATCH 1024
#define SEQ   512

typedef float f32x4 __attribute__((ext_vector_type(4)));

// Kernel A: EWx[v][j] = sum_e E[v][e]*Wx[e][j] + b[j]   (folds bias in)
__global__ __launch_bounds__(256) void ewx_kernel(
    const float* __restrict__ E, const float* __restrict__ Wx,
    const float* __restrict__ bias, float* __restrict__ EWx)
{
    __shared__ float Es[64][EMB];     // 25.6 KB
    __shared__ float Wxs[EMB][HID];   // 51.2 KB
    const int tid = threadIdx.x;
    const int v0 = blockIdx.x * 64;
    const int nv = min(64, VOCAB - v0);

    {
        const float4* s4 = (const float4*)Wx;
        float4* d4 = (float4*)(&Wxs[0][0]);
        for (int i = tid; i < (EMB * HID) / 4; i += 256) d4[i] = s4[i];
    }
    {
        const float* src = E + (size_t)v0 * EMB;
        float* dst = &Es[0][0];
        const int n  = nv * EMB;
        const int n4 = n >> 2;
        const float4* s4 = (const float4*)src;
        float4* d4 = (float4*)dst;
        for (int i = tid; i < n4; i += 256) d4[i] = s4[i];
        for (int i = (n4 << 2) + tid; i < n; i += 256) dst[i] = src[i];
    }
    __syncthreads();

    const int j  = tid & 127;
    const int vh = tid >> 7;
    float acc[32];
#pragma unroll
    for (int m = 0; m < 32; ++m) acc[m] = 0.f;

    for (int k4 = 0; k4 < EMB; k4 += 4) {
        const float w0 = Wxs[k4 + 0][j];
        const float w1 = Wxs[k4 + 1][j];
        const float w2 = Wxs[k4 + 2][j];
        const float w3 = Wxs[k4 + 3][j];
#pragma unroll
        for (int m = 0; m < 32; ++m) {
            const float4 e = *(const float4*)&Es[vh + 2 * m][k4];
            acc[m] = fmaf(e.x, w0, acc[m]);
            acc[m] = fmaf(e.y, w1, acc[m]);
            acc[m] = fmaf(e.z, w2, acc[m]);
            acc[m] = fmaf(e.w, w3, acc[m]);
        }
    }
    const float bj = bias[j];
#pragma unroll
    for (int m = 0; m < 32; ++m) {
        const int v = vh + 2 * m;
        if (v < nv)
            EWx[(size_t)(v0 + v) * HID + j] = acc[m] + bj;
    }
}

// Kernel B: sequential recurrence.
// Block = 256 threads, 2 batch rows. Thread = (kq = tid>>5 in 0..7,
// jc = tid&31): owns Wh[kq*16 .. +15][4jc .. 4jc+3] = 64 weights held in
// 64 NAMED SCALARS (W0_0..W15_3). History: plain array -> compiler remats
// global loads into the loop (r2: VGPR=84); array + asm pins -> array
// forced to scratch (r3: VGPR=80, r4: VGPR=48). Named scalars cannot be
// dynamically indexed, so neither failure mode applies.
// Per step: 8 broadcast ds_read_b128 of h (2 addrs/wave, conflict-free)
// -> 128 FMAs -> b128 partial writes -> barrier -> 8-way stride-1 reduce
// + tanh -> h_new write -> barrier.
__global__ __launch_bounds__(256, 2) void rnn_kernel(
    const int* __restrict__ X, const float* __restrict__ EWx,
    const float* __restrict__ Wh, const float* __restrict__ Wd,
    const float* __restrict__ bd, float* __restrict__ out)
{
    __shared__ __align__(16) float hbuf[2][2][HID];  // 2 KB, double-buffered
    __shared__ __align__(16) float part[2][8][HID];  // 8 KB partials
    __shared__ int idx[2][SEQ];                      // 4 KB token indices

    const int tid = threadIdx.x;
    const int kq  = tid >> 5;          // k-slice [kq*16, kq*16+16)
    const int jc  = tid & 31;          // column quad: cols 4jc..4jc+3
    const int b0  = blockIdx.x * 2;

    for (int i = tid; i < 2 * SEQ; i += 256) {
        idx[i >> 9][i & 511] = X[(size_t)(b0 + (i >> 9)) * SEQ + (i & 511)];
    }

#define DECLW(kk) float W##kk##_0, W##kk##_1, W##kk##_2, W##kk##_3;
    DECLW(0)  DECLW(1)  DECLW(2)  DECLW(3)
    DECLW(4)  DECLW(5)  DECLW(6)  DECLW(7)
    DECLW(8)  DECLW(9)  DECLW(10) DECLW(11)
    DECLW(12) DECLW(13) DECLW(14) DECLW(15)
#undef DECLW

#define LOADW(kk) { const f32x4 w_ = *reinterpret_cast<const f32x4*>(      \
        &Wh[(size_t)(kq * 16 + kk) * HID + 4 * jc]);                       \
        W##kk##_0 = w_.x; W##kk##_1 = w_.y;                                \
        W##kk##_2 = w_.z; W##kk##_3 = w_.w; }
    LOADW(0)  LOADW(1)  LOADW(2)  LOADW(3)
    LOADW(4)  LOADW(5)  LOADW(6)  LOADW(7)
    LOADW(8)  LOADW(9)  LOADW(10) LOADW(11)
    LOADW(12) LOADW(13) LOADW(14) LOADW(15)
#undef LOADW

    (&hbuf[0][0][0])[tid] = 0.f;       // h0 = 0 (256 floats)
    __syncthreads();

    const int rf = tid >> 7;           // row this thread finalizes
    const int cf = tid & 127;          // column this thread finalizes

    int cur = 0;
    for (int t = 0; t < SEQ; ++t) {
        // issue xp gather early; consumed at finalize (hidden under FMAs)
        const int   tok = idx[rf][t];
        const float xp  = EWx[(size_t)tok * HID + cf];

        const f32x4* h0 = (const f32x4*)&hbuf[cur][0][kq * 16];
        const f32x4* h1 = (const f32x4*)&hbuf[cur][1][kq * 16];
        float a00 = 0.f, a01 = 0.f, a02 = 0.f, a03 = 0.f;  // row 0, 4 cols
        float a10 = 0.f, a11 = 0.f, a12 = 0.f, a13 = 0.f;  // row 1, 4 cols

#define FMA8(kk, hv0, hv1)                                                  \
        a00 = fmaf(hv0, W##kk##_0, a00); a01 = fmaf(hv0, W##kk##_1, a01);   \
        a02 = fmaf(hv0, W##kk##_2, a02); a03 = fmaf(hv0, W##kk##_3, a03);   \
        a10 = fmaf(hv1, W##kk##_0, a10); a11 = fmaf(hv1, W##kk##_1, a11);   \
        a12 = fmaf(hv1, W##kk##_2, a12); a13 = fmaf(hv1, W##kk##_3, a13);

        { const f32x4 u0 = h0[0], u1 = h1[0];
          FMA8(0,  u0.x, u1.x) FMA8(1,  u0.y, u1.y)
          FMA8(2,  u0.z, u1.z) FMA8(3,  u0.w, u1.w) }
        { const f32x4 u0 = h0[1], u1 = h1[1];
          FMA8(4,  u0.x, u1.x) FMA8(5,  u0.y, u1.y)
          FMA8(6,  u0.z, u1.z) FMA8(7,  u0.w, u1.w) }
        { const f32x4 u0 = h0[2], u1 = h1[2];
          FMA8(8,  u0.x, u1.x) FMA8(9,  u0.y, u1.y)
          FMA8(10, u0.z, u1.z) FMA8(11, u0.w, u1.w) }
        { const f32x4 u0 = h0[3], u1 = h1[3];
          FMA8(12, u0.x, u1.x) FMA8(13, u0.y, u1.y)
          FMA8(14, u0.z, u1.z) FMA8(15, u0.w, u1.w) }
#undef FMA8

        // contiguous b128 partial writes (conflict-free)
        { f32x4 p0; p0.x = a00; p0.y = a01; p0.z = a02; p0.w = a03;
          *reinterpret_cast<f32x4*>(&part[0][kq][4 * jc]) = p0; }
        { f32x4 p1; p1.x = a10; p1.y = a11; p1.z = a12; p1.w = a13;
          *reinterpret_cast<f32x4*>(&part[1][kq][4 * jc]) = p1; }
        __syncthreads();

        // finalize (rf, cf): 8-way reduce (stride-1 b32 reads) + xp + tanh
        float s = xp;
#pragma unroll
        for (int k = 0; k < 8; ++k) s += part[rf][k][cf];
        const float x  = fminf(fmaxf(s, -9.f), 9.f);  // tanh saturates past 9
        const float e2 = __expf(2.f * x);
        hbuf[cur ^ 1][rf][cf] = __fdividef(e2 - 1.f, e2 + 1.f);
        __syncthreads();
        cur ^= 1;
    }

    // head: out[b] = sigmoid(h . Wd + bd)
    if (tid < 128) {
        const int bb   = tid >> 6;
        const int lane = tid & 63;
        const float* hb = hbuf[cur][bb];
        float v = hb[lane] * Wd[lane] + hb[lane + 64] * Wd[lane + 64];
#pragma unroll
        for (int off = 32; off > 0; off >>= 1)
            v += __shfl_down(v, off, 64);
        if (lane == 0)
            out[b0 + bb] = 1.0f / (1.0f + expf(-(v + bd[0])));
    }
}

extern "C" void kernel_launch(void* const* d_in, const int* in_sizes, int n_in,
                              void* d_out, int out_size, void* d_ws, size_t ws_size,
                              hipStream_t stream)
{
    const int*   X  = (const int*)d_in[0];
    const float* E  = (const float*)d_in[1];
    const float* Wx = (const float*)d_in[2];
    const float* Wh = (const float*)d_in[3];
    const float* b  = (const float*)d_in[4];
    const float* Wd = (const float*)d_in[5];
    const float* bd = (const float*)d_in[6];
    float* out = (float*)d_out;
    float* EWx = (float*)d_ws;   // 30000*128*4 = 15.36 MB scratch

    ewx_kernel<<<dim3((VOCAB + 63) / 64), dim3(256), 0, stream>>>(E, Wx, b, EWx);
    rnn_kernel<<<dim3(BATCH / 2), dim3(256), 0, stream>>>(X, EWx, Wh, Wd, bd, out);
}